// Round 5
// baseline (165.565 us; speedup 1.0000x reference)
//
#include <hip/hip_runtime.h>
#include <hip/hip_bf16.h>

// Problem: T=2048, B=32, H=512
//   scores[b,t] = sum_o v[o] * tanh( hb[b,o] + sum_h enc[t,b,h] * W2[o,h] )
//   out[b,0,t]  = softmax_t(scores[b,:])
// where hb[b,o] = sum_h hidden[b,h]*W_attn[o,h] + b_attn[o],  W2[o,h] = W_attn[o, 512+h]
//
// R3 lesson: fragment-major W2 repack poisoned the memory system (FETCH 70->292MB,
// WRITE 0.25->121MB); row-major W2b + this staging pattern is the verified-good
// memory structure — do not change it.
// R4 -> R5: latency-bound at 2 waves/SIMD (MfmaUtil 11%, VALU 18%, HBM 7.5%).
// One change: 8-wave 2D split (wm x wn = 2x4), 512 threads. Doubles waves/SIMD,
// halves per-wave A-LDS traffic and epilogue length. Layouts untouched.

#define TT 2048
#define BB 32
#define HH 512

typedef __attribute__((ext_vector_type(8))) short bf16x8;
typedef __attribute__((ext_vector_type(4))) float f32x4;

static __device__ __forceinline__ unsigned cvt2(float a, float b) {
    union { __hip_bfloat162 h; unsigned u; } cv;
    cv.h = __float22bfloat162_rn(make_float2(a, b));   // v_cvt_pk_bf16_f32
    return cv.u;
}

static __device__ __forceinline__ unsigned short f2bf(float f) {
    unsigned int u = __float_as_uint(f);
    unsigned int r = (u + 0x7FFFu + ((u >> 16) & 1u)) >> 16;  // RNE
    return (unsigned short)r;
}

// tanh(x) = 1 - 2/(1+e^{2x});  e=inf -> rcp(inf)=0 -> +1;  e=0 -> -1. Inf-safe.
static __device__ __forceinline__ float fast_tanh(float x) {
    float e = __expf(2.0f * x);
    return 1.0f - 2.0f * __builtin_amdgcn_rcpf(1.0f + e);
}

// ---- Kernel 1: convert W2 (= W_attn[:, 512:1024]) to bf16, row-major [512][512]
__global__ void conv_w2_kernel(const float* __restrict__ W, short* __restrict__ W2b) {
    int i = blockIdx.x * 256 + threadIdx.x;        // 262144 total
    int o = i >> 9, h = i & 511;
    W2b[i] = (short)f2bf(W[o * 1024 + 512 + h]);
}

// ---- Kernel 2: hb[b][o] = b_attn[o] + sum_h hidden[b,h] * W_attn[o,h]
__global__ void hb_kernel(const float* __restrict__ hidden, const float* __restrict__ W,
                          const float* __restrict__ b_attn, float* __restrict__ hb) {
    __shared__ float hrow[512];
    int b = blockIdx.x >> 1;
    int o = ((blockIdx.x & 1) << 8) + threadIdx.x;
    for (int h = threadIdx.x; h < 512; h += 256) hrow[h] = hidden[b * 512 + h];
    __syncthreads();
    const float4* wr = reinterpret_cast<const float4*>(W + (size_t)o * 1024);
    const float4* hr = reinterpret_cast<const float4*>(hrow);
    float acc = b_attn[o];
#pragma unroll 8
    for (int i = 0; i < 128; ++i) {
        float4 w = wr[i], h4 = hr[i];
        acc += w.x * h4.x + w.y * h4.y + w.z * h4.z + w.w * h4.w;
    }
    hb[b * 512 + o] = acc;
}

// ---- Kernel 3: fused GEMM + tanh + v-dot -> scores[b][t]
// Block: 512 threads (8 waves as wm x wn = 2 x 4). Tile: 64 t-rows for one b,
// full K=512 in LDS (bf16, swizzled). Wave (wm,wn): rows wm*32..+32,
// cols chunk*256 + wn*64..+64, chunk in {0,1}.
__global__ __launch_bounds__(512, 4) void attn_main_kernel(
    const float* __restrict__ enc, const short* __restrict__ W2b,
    const float* __restrict__ hb, const float* __restrict__ v,
    float* __restrict__ scores)
{
    __shared__ short At[64 * 512];   // 64KB, swizzled: idx = (m*512+c) ^ ((m&7)<<3)
    __shared__ float s_red[4][64];

    const int tid = threadIdx.x;
    const int b = blockIdx.x >> 5;          // 32 b's
    const int t0 = (blockIdx.x & 31) * 64;  // 32 t-blocks

    // ---- stage enc tile -> LDS bf16 (coalesced fp32 reads, cvt_pk conversion)
    {
        const int rsub = tid >> 7;          // 0..3
        const int c4 = (tid & 127) * 4;     // 0..508
#pragma unroll 4
        for (int p = 0; p < 16; ++p) {
            const int m = p * 4 + rsub;
            const float4 vld = *reinterpret_cast<const float4*>(
                &enc[(size_t)((t0 + m) * BB + b) * HH + c4]);
            uint2 pk;
            pk.x = cvt2(vld.x, vld.y);
            pk.y = cvt2(vld.z, vld.w);
            const int idx = (m * 512 + c4) ^ ((m & 7) << 3);
            *reinterpret_cast<uint2*>(&At[idx]) = pk;
        }
    }
    __syncthreads();

    const int wave = tid >> 6;
    const int wm = wave >> 2;             // 0..1 : row half
    const int wn = wave & 3;              // 0..3 : col quarter
    const int lane = tid & 63;
    const int lrow = lane & 15;           // A row / B col / D col
    const int lk = (lane >> 4) * 8;       // k sub-offset

    float score_acc[2][4];                 // [mt][reg] ; row = wm*32 + mt*16 + (lane>>4)*4 + r
#pragma unroll
    for (int i = 0; i < 2; ++i)
#pragma unroll
        for (int j = 0; j < 4; ++j) score_acc[i][j] = 0.0f;

    for (int chunk = 0; chunk < 2; ++chunk) {
        const int cb = chunk * 256 + wn * 64;   // this wave's 64-col base

        f32x4 acc[2][4];
#pragma unroll
        for (int mt = 0; mt < 2; ++mt)
#pragma unroll
            for (int ns = 0; ns < 4; ++ns) acc[mt][ns] = (f32x4){0.f, 0.f, 0.f, 0.f};

#pragma unroll 4
        for (int ks = 0; ks < 16; ++ks) {
            const int kc = ks * 32 + lk;
            bf16x8 a[2], bf[4];
#pragma unroll
            for (int mt = 0; mt < 2; ++mt) {
                const int m = wm * 32 + mt * 16 + lrow;
                const int idx = (m * 512 + kc) ^ ((m & 7) << 3);
                a[mt] = *reinterpret_cast<const bf16x8*>(&At[idx]);
            }
#pragma unroll
            for (int ns = 0; ns < 4; ++ns) {
                const int o = cb + ns * 16 + lrow;
                bf[ns] = *reinterpret_cast<const bf16x8*>(&W2b[o * 512 + kc]);
            }
#pragma unroll
            for (int mt = 0; mt < 2; ++mt)
#pragma unroll
                for (int ns = 0; ns < 4; ++ns)
                    acc[mt][ns] = __builtin_amdgcn_mfma_f32_16x16x32_bf16(
                        a[mt], bf[ns], acc[mt][ns], 0, 0, 0);
        }

        // epilogue for this chunk: tanh + v-weighted accumulate into row partials
#pragma unroll
        for (int ns = 0; ns < 4; ++ns) {
            const int o = cb + ns * 16 + lrow;
            const float hbv = hb[b * 512 + o];
            const float vv = v[o];
#pragma unroll
            for (int mt = 0; mt < 2; ++mt)
#pragma unroll
                for (int r = 0; r < 4; ++r) {
                    const float x = acc[mt][ns][r] + hbv;
                    score_acc[mt][r] = fmaf(fast_tanh(x), vv, score_acc[mt][r]);
                }
        }
    }

    // reduce across the 16 columns held by lanes (low 4 lane bits)
#pragma unroll
    for (int off = 1; off < 16; off <<= 1)
#pragma unroll
        for (int mt = 0; mt < 2; ++mt)
#pragma unroll
            for (int r = 0; r < 4; ++r)
                score_acc[mt][r] += __shfl_xor(score_acc[mt][r], off, 64);

    if (lrow == 0) {
        const int rbase = (lane >> 4) * 4;
#pragma unroll
        for (int mt = 0; mt < 2; ++mt)
#pragma unroll
            for (int r = 0; r < 4; ++r)
                s_red[wn][wm * 32 + mt * 16 + rbase + r] = score_acc[mt][r];
    }
    __syncthreads();

    if (tid < 64)
        scores[(size_t)b * TT + t0 + tid] =
            s_red[0][tid] + s_red[1][tid] + s_red[2][tid] + s_red[3][tid];
}

// ---- Kernel 4: softmax over T per b
__global__ void softmax_kernel(const float* __restrict__ scores, float* __restrict__ out) {
    __shared__ float wred[4];
    __shared__ float wsum[4];
    const int b = blockIdx.x;
    const int tid = threadIdx.x;   // 256
    float vals[8];
    float mx = -1e30f;
#pragma unroll
    for (int i = 0; i < 8; ++i) {
        vals[i] = scores[b * TT + i * 256 + tid];
        mx = fmaxf(mx, vals[i]);
    }
#pragma unroll
    for (int off = 32; off; off >>= 1) mx = fmaxf(mx, __shfl_xor(mx, off, 64));
    if ((tid & 63) == 0) wred[tid >> 6] = mx;
    __syncthreads();
    mx = fmaxf(fmaxf(wred[0], wred[1]), fmaxf(wred[2], wred[3]));
    float s = 0.0f;
#pragma unroll
    for (int i = 0; i < 8; ++i) {
        vals[i] = __expf(vals[i] - mx);
        s += vals[i];
    }
#pragma unroll
    for (int off = 32; off; off >>= 1) s += __shfl_xor(s, off, 64);
    if ((tid & 63) == 0) wsum[tid >> 6] = s;
    __syncthreads();
    s = wsum[0] + wsum[1] + wsum[2] + wsum[3];
    const float inv = 1.0f / s;
#pragma unroll
    for (int i = 0; i < 8; ++i) out[b * TT + i * 256 + tid] = vals[i] * inv;
}

extern "C" void kernel_launch(void* const* d_in, const int* in_sizes, int n_in,
                              void* d_out, int out_size, void* d_ws, size_t ws_size,
                              hipStream_t stream) {
    const float* hidden = (const float*)d_in[0];   // (1,B,H)
    const float* enc    = (const float*)d_in[1];   // (T,B,H)
    const float* W      = (const float*)d_in[2];   // (H,2H)
    const float* b_attn = (const float*)d_in[3];   // (H,)
    const float* v      = (const float*)d_in[4];   // (H,)
    float* out = (float*)d_out;                    // (B,1,T)

    char* base = (char*)d_ws;
    short* W2b   = (short*)base;                       // 512*512*2 = 524288 B
    float* hb    = (float*)(base + 524288);            // 32*512*4  =  65536 B
    float* scores= (float*)(base + 524288 + 65536);    // 32*2048*4 = 262144 B

    conv_w2_kernel<<<1024, 256, 0, stream>>>(W, W2b);
    hb_kernel<<<64, 256, 0, stream>>>(hidden, W, b_attn, hb);
    attn_main_kernel<<<1024, 512, 0, stream>>>(enc, W2b, hb, v, scores);
    softmax_kernel<<<32, 256, 0, stream>>>(scores, out);
}

// Round 6
// 161.967 us; speedup vs baseline: 1.0222x; 1.0222x over previous
//
#include <hip/hip_runtime.h>
#include <hip/hip_bf16.h>

// Problem: T=2048, B=32, H=512
//   scores[b,t] = sum_o v[o] * tanh( hb[b,o] + sum_h enc[t,b,h] * W2[o,h] )
//   out[b,0,t]  = softmax_t(scores[b,:])
// where hb[b,o] = sum_h hidden[b,h]*W_attn[o,h] + b_attn[o],  W2[o,h] = W_attn[o, 512+h]
//
// HARD-WON RULES (R2/R3/R5 post-mortems):
//  - WRITE_SIZE >> 1MB == register spill to scratch. VGPR_Count=64 is the spill
//    signature: __launch_bounds__ min-waves>=4 caps arch VGPRs at 64 on gfx950
//    (unified VGPR/AGPR file) and the kernel spills. NEVER use min-waves >= 4.
//  - Row-major W2b + this staging pattern is verified good (70MB FETCH). Keep.
// R5->R6: same 8-wave 2x4 split as R5 but lb(512,2): spill-free occupancy test.

#define TT 2048
#define BB 32
#define HH 512

typedef __attribute__((ext_vector_type(8))) short bf16x8;
typedef __attribute__((ext_vector_type(4))) float f32x4;

static __device__ __forceinline__ unsigned cvt2(float a, float b) {
    union { __hip_bfloat162 h; unsigned u; } cv;
    cv.h = __float22bfloat162_rn(make_float2(a, b));   // v_cvt_pk_bf16_f32
    return cv.u;
}

static __device__ __forceinline__ unsigned short f2bf(float f) {
    unsigned int u = __float_as_uint(f);
    unsigned int r = (u + 0x7FFFu + ((u >> 16) & 1u)) >> 16;  // RNE
    return (unsigned short)r;
}

// tanh(x) = 1 - 2/(1+e^{2x});  e=inf -> rcp(inf)=0 -> +1;  e=0 -> -1. Inf-safe.
static __device__ __forceinline__ float fast_tanh(float x) {
    float e = __expf(2.0f * x);
    return 1.0f - 2.0f * __builtin_amdgcn_rcpf(1.0f + e);
}

// ---- Kernel 1: convert W2 (= W_attn[:, 512:1024]) to bf16, row-major [512][512]
__global__ void conv_w2_kernel(const float* __restrict__ W, short* __restrict__ W2b) {
    int i = blockIdx.x * 256 + threadIdx.x;        // 262144 total
    int o = i >> 9, h = i & 511;
    W2b[i] = (short)f2bf(W[o * 1024 + 512 + h]);
}

// ---- Kernel 2: hb[b][o] = b_attn[o] + sum_h hidden[b,h] * W_attn[o,h]
__global__ void hb_kernel(const float* __restrict__ hidden, const float* __restrict__ W,
                          const float* __restrict__ b_attn, float* __restrict__ hb) {
    __shared__ float hrow[512];
    int b = blockIdx.x >> 1;
    int o = ((blockIdx.x & 1) << 8) + threadIdx.x;
    for (int h = threadIdx.x; h < 512; h += 256) hrow[h] = hidden[b * 512 + h];
    __syncthreads();
    const float4* wr = reinterpret_cast<const float4*>(W + (size_t)o * 1024);
    const float4* hr = reinterpret_cast<const float4*>(hrow);
    float acc = b_attn[o];
#pragma unroll 8
    for (int i = 0; i < 128; ++i) {
        float4 w = wr[i], h4 = hr[i];
        acc += w.x * h4.x + w.y * h4.y + w.z * h4.z + w.w * h4.w;
    }
    hb[b * 512 + o] = acc;
}

// ---- Kernel 3: fused GEMM + tanh + v-dot -> scores[b][t]
// Block: 512 threads (8 waves, wm x wn = 2 x 4). Tile: 64 t-rows for one b,
// full K=512 in LDS (bf16, swizzled). Wave (wm,wn): rows wm*32..+32,
// cols chunk*128 + wn*32..+32, chunk in {0..3}.
// lb(512,2): VGPR cap 256 (spill-free); LDS 66KB caps at 2 blocks/CU = 4 waves/SIMD.
__global__ __launch_bounds__(512, 2) void attn_main_kernel(
    const float* __restrict__ enc, const short* __restrict__ W2b,
    const float* __restrict__ hb, const float* __restrict__ v,
    float* __restrict__ scores)
{
    __shared__ short At[64 * 512];   // 64KB, swizzled: idx = (m*512+c) ^ ((m&7)<<3)
    __shared__ float s_red[4][64];

    const int tid = threadIdx.x;
    const int b = blockIdx.x >> 5;          // 32 b's
    const int t0 = (blockIdx.x & 31) * 64;  // 32 t-blocks

    // ---- stage enc tile -> LDS bf16 (coalesced fp32 reads, cvt_pk conversion)
    {
        const int rsub = tid >> 7;          // 0..3
        const int c4 = (tid & 127) * 4;     // 0..508
#pragma unroll 4
        for (int p = 0; p < 16; ++p) {
            const int m = p * 4 + rsub;
            const float4 vld = *reinterpret_cast<const float4*>(
                &enc[(size_t)((t0 + m) * BB + b) * HH + c4]);
            uint2 pk;
            pk.x = cvt2(vld.x, vld.y);
            pk.y = cvt2(vld.z, vld.w);
            const int idx = (m * 512 + c4) ^ ((m & 7) << 3);
            *reinterpret_cast<uint2*>(&At[idx]) = pk;
        }
    }
    __syncthreads();

    const int wave = tid >> 6;
    const int wm = wave >> 2;             // 0..1 : row half
    const int wn = wave & 3;              // 0..3 : col quarter
    const int lane = tid & 63;
    const int lrow = lane & 15;           // A row / B col / D col
    const int lk = (lane >> 4) * 8;       // k sub-offset

    float score_acc[2][4];                 // [mt][reg] ; row = wm*32 + mt*16 + (lane>>4)*4 + r
#pragma unroll
    for (int i = 0; i < 2; ++i)
#pragma unroll
        for (int j = 0; j < 4; ++j) score_acc[i][j] = 0.0f;

#pragma unroll
    for (int chunk = 0; chunk < 4; ++chunk) {
        const int cb = chunk * 128 + wn * 32;   // this wave's 32-col base

        f32x4 acc[2][2];
#pragma unroll
        for (int mt = 0; mt < 2; ++mt)
#pragma unroll
            for (int ns = 0; ns < 2; ++ns) acc[mt][ns] = (f32x4){0.f, 0.f, 0.f, 0.f};

#pragma unroll 4
        for (int ks = 0; ks < 16; ++ks) {
            const int kc = ks * 32 + lk;
            bf16x8 a[2], bf[2];
#pragma unroll
            for (int mt = 0; mt < 2; ++mt) {
                const int m = wm * 32 + mt * 16 + lrow;
                const int idx = (m * 512 + kc) ^ ((m & 7) << 3);
                a[mt] = *reinterpret_cast<const bf16x8*>(&At[idx]);
            }
#pragma unroll
            for (int ns = 0; ns < 2; ++ns) {
                const int o = cb + ns * 16 + lrow;
                bf[ns] = *reinterpret_cast<const bf16x8*>(&W2b[o * 512 + kc]);
            }
#pragma unroll
            for (int mt = 0; mt < 2; ++mt)
#pragma unroll
                for (int ns = 0; ns < 2; ++ns)
                    acc[mt][ns] = __builtin_amdgcn_mfma_f32_16x16x32_bf16(
                        a[mt], bf[ns], acc[mt][ns], 0, 0, 0);
        }

        // epilogue for this chunk: tanh + v-weighted accumulate into row partials
#pragma unroll
        for (int ns = 0; ns < 2; ++ns) {
            const int o = cb + ns * 16 + lrow;
            const float hbv = hb[b * 512 + o];
            const float vv = v[o];
#pragma unroll
            for (int mt = 0; mt < 2; ++mt)
#pragma unroll
                for (int r = 0; r < 4; ++r) {
                    const float x = acc[mt][ns][r] + hbv;
                    score_acc[mt][r] = fmaf(fast_tanh(x), vv, score_acc[mt][r]);
                }
        }
    }

    // reduce across the 16 columns held by lanes (low 4 lane bits)
#pragma unroll
    for (int off = 1; off < 16; off <<= 1)
#pragma unroll
        for (int mt = 0; mt < 2; ++mt)
#pragma unroll
            for (int r = 0; r < 4; ++r)
                score_acc[mt][r] += __shfl_xor(score_acc[mt][r], off, 64);

    if (lrow == 0) {
        const int rbase = (lane >> 4) * 4;
#pragma unroll
        for (int mt = 0; mt < 2; ++mt)
#pragma unroll
            for (int r = 0; r < 4; ++r)
                s_red[wn][wm * 32 + mt * 16 + rbase + r] = score_acc[mt][r];
    }
    __syncthreads();

    if (tid < 64)
        scores[(size_t)b * TT + t0 + tid] =
            s_red[0][tid] + s_red[1][tid] + s_red[2][tid] + s_red[3][tid];
}

// ---- Kernel 4: softmax over T per b
__global__ void softmax_kernel(const float* __restrict__ scores, float* __restrict__ out) {
    __shared__ float wred[4];
    __shared__ float wsum[4];
    const int b = blockIdx.x;
    const int tid = threadIdx.x;   // 256
    float vals[8];
    float mx = -1e30f;
#pragma unroll
    for (int i = 0; i < 8; ++i) {
        vals[i] = scores[b * TT + i * 256 + tid];
        mx = fmaxf(mx, vals[i]);
    }
#pragma unroll
    for (int off = 32; off; off >>= 1) mx = fmaxf(mx, __shfl_xor(mx, off, 64));
    if ((tid & 63) == 0) wred[tid >> 6] = mx;
    __syncthreads();
    mx = fmaxf(fmaxf(wred[0], wred[1]), fmaxf(wred[2], wred[3]));
    float s = 0.0f;
#pragma unroll
    for (int i = 0; i < 8; ++i) {
        vals[i] = __expf(vals[i] - mx);
        s += vals[i];
    }
#pragma unroll
    for (int off = 32; off; off >>= 1) s += __shfl_xor(s, off, 64);
    if ((tid & 63) == 0) wsum[tid >> 6] = s;
    __syncthreads();
    s = wsum[0] + wsum[1] + wsum[2] + wsum[3];
    const float inv = 1.0f / s;
#pragma unroll
    for (int i = 0; i < 8; ++i) out[b * TT + i * 256 + tid] = vals[i] * inv;
}

extern "C" void kernel_launch(void* const* d_in, const int* in_sizes, int n_in,
                              void* d_out, int out_size, void* d_ws, size_t ws_size,
                              hipStream_t stream) {
    const float* hidden = (const float*)d_in[0];   // (1,B,H)
    const float* enc    = (const float*)d_in[1];   // (T,B,H)
    const float* W      = (const float*)d_in[2];   // (H,2H)
    const float* b_attn = (const float*)d_in[3];   // (H,)
    const float* v      = (const float*)d_in[4];   // (H,)
    float* out = (float*)d_out;                    // (B,1,T)

    char* base = (char*)d_ws;
    short* W2b   = (short*)base;                       // 512*512*2 = 524288 B
    float* hb    = (float*)(base + 524288);            // 32*512*4  =  65536 B
    float* scores= (float*)(base + 524288 + 65536);    // 32*2048*4 = 262144 B

    conv_w2_kernel<<<1024, 256, 0, stream>>>(W, W2b);
    hb_kernel<<<64, 256, 0, stream>>>(hidden, W, b_attn, hb);
    attn_main_kernel<<<1024, 512, 0, stream>>>(enc, W2b, hb, v, scores);
    softmax_kernel<<<32, 256, 0, stream>>>(scores, out);
}

// Round 7
// 137.933 us; speedup vs baseline: 1.2003x; 1.1742x over previous
//
#include <hip/hip_runtime.h>
#include <hip/hip_bf16.h>

// Problem: T=2048, B=32, H=512
//   scores[b,t] = sum_o v[o] * tanh( hb[b,o] + sum_h enc[t,b,h] * W2[o,h] )
//   out[b,0,t]  = softmax_t(scores[b,:])
//
// HARD-WON RULES (R2/R3/R5/R6 post-mortems):
//  - WRITE_SIZE >> 1MB == scratch spill; VGPR_Count 60-64 is the squeezed-allocator
//    signature. Never request >=4 waves/EU via __launch_bounds__.
//  - Row-major W2b + the R0 staging pattern is the verified-good memory structure.
//  - Occupancy is NOT the lever (R6: 44% occ, spill-free, still slower). Lockstep
//    waves don't hide each other's latency. The lever is ILP: keep B-loads ~2
//    ks-steps ahead of use within each wave.

#define TT 2048
#define BB 32
#define HH 512

typedef __attribute__((ext_vector_type(8))) short bf16x8;
typedef __attribute__((ext_vector_type(4))) float f32x4;

static __device__ __forceinline__ unsigned cvt2(float a, float b) {
    union { __hip_bfloat162 h; unsigned u; } cv;
    cv.h = __float22bfloat162_rn(make_float2(a, b));   // v_cvt_pk_bf16_f32
    return cv.u;
}

static __device__ __forceinline__ unsigned short f2bf(float f) {
    unsigned int u = __float_as_uint(f);
    unsigned int r = (u + 0x7FFFu + ((u >> 16) & 1u)) >> 16;  // RNE
    return (unsigned short)r;
}

// tanh(x) = 1 - 2/(1+e^{2x});  inf-safe at both ends.
static __device__ __forceinline__ float fast_tanh(float x) {
    float e = __expf(2.0f * x);
    return 1.0f - 2.0f * __builtin_amdgcn_rcpf(1.0f + e);
}

// ---- Kernel 1: convert W2 (= W_attn[:, 512:1024]) to bf16, row-major [512][512]
__global__ void conv_w2_kernel(const float* __restrict__ W, short* __restrict__ W2b) {
    int i = blockIdx.x * 256 + threadIdx.x;        // 262144 total
    int o = i >> 9, h = i & 511;
    W2b[i] = (short)f2bf(W[o * 1024 + 512 + h]);
}

// ---- Kernel 2: hb[b][o] = b_attn[o] + sum_h hidden[b,h] * W_attn[o,h]
__global__ void hb_kernel(const float* __restrict__ hidden, const float* __restrict__ W,
                          const float* __restrict__ b_attn, float* __restrict__ hb) {
    __shared__ float hrow[512];
    int b = blockIdx.x >> 1;
    int o = ((blockIdx.x & 1) << 8) + threadIdx.x;
    for (int h = threadIdx.x; h < 512; h += 256) hrow[h] = hidden[b * 512 + h];
    __syncthreads();
    const float4* wr = reinterpret_cast<const float4*>(W + (size_t)o * 1024);
    const float4* hr = reinterpret_cast<const float4*>(hrow);
    float acc = b_attn[o];
#pragma unroll 8
    for (int i = 0; i < 128; ++i) {
        float4 w = wr[i], h4 = hr[i];
        acc += w.x * h4.x + w.y * h4.y + w.z * h4.z + w.w * h4.w;
    }
    hb[b * 512 + o] = acc;
}

// ---- Kernel 3: fused GEMM + tanh + v-dot -> scores[b][t]
// Block: 256 threads (4 waves). Tile: 64 t-rows for one b, full K=512 in LDS
// (bf16, swizzled). o in 4 chunks of 128; wave w owns cols chunk*128+w*32..+32.
// NEW (R7): rotating 2-deep register prefetch of B fragments across the whole
// 64-step (chunk,ks) sequence, carried across chunk boundaries so the tanh
// epilogue overlaps the next chunk's lead-in B-latency.
__global__ __launch_bounds__(256, 2) void attn_main_kernel(
    const float* __restrict__ enc, const short* __restrict__ W2b,
    const float* __restrict__ hb, const float* __restrict__ v,
    float* __restrict__ scores)
{
    __shared__ short At[64 * 512];   // 64KB, swizzled: idx = (m*512+c) ^ ((m&7)<<3)
    __shared__ float s_red[4][64];

    const int tid = threadIdx.x;
    const int b = blockIdx.x >> 5;          // 32 b's
    const int t0 = (blockIdx.x & 31) * 64;  // 32 t-blocks

    // ---- stage enc tile -> LDS bf16 (coalesced fp32 reads, cvt_pk conversion)
    {
        const int rsub = tid >> 7;          // 0..1
        const int c4 = (tid & 127) * 4;     // 0..508
#pragma unroll 4
        for (int p = 0; p < 32; ++p) {
            const int m = p * 2 + rsub;
            const float4 vld = *reinterpret_cast<const float4*>(
                &enc[(size_t)((t0 + m) * BB + b) * HH + c4]);
            uint2 pk;
            pk.x = cvt2(vld.x, vld.y);
            pk.y = cvt2(vld.z, vld.w);
            const int idx = (m * 512 + c4) ^ ((m & 7) << 3);
            *reinterpret_cast<uint2*>(&At[idx]) = pk;
        }
    }
    __syncthreads();

    const int wave = tid >> 6;
    const int lane = tid & 63;
    const int lrow = lane & 15;           // A row / B col / D col
    const int lk = (lane >> 4) * 8;       // k sub-offset

    // Per-lane base for this wave's B fragments:
    //   addr(l, ns) = (chunk(l)*128 + wave*32 + ns*16 + lrow)*512 + (l&15)*32 + lk
    // where l = linear (chunk*16 + ks) in [0,64).
    const short* Bbase = W2b + (wave * 32 + lrow) * 512 + lk;

    float score_acc[4][4];                 // [m_tile][reg] ; row = mt*16 + (lane>>4)*4 + r
#pragma unroll
    for (int i = 0; i < 4; ++i)
#pragma unroll
        for (int j = 0; j < 4; ++j) score_acc[i][j] = 0.0f;

    // rotating 2-deep B prefetch, carried across chunks
    bf16x8 bc[2], bn[2], bp0[2], bp1[2];
#pragma unroll
    for (int ns = 0; ns < 2; ++ns) {
        bc[ns] = *reinterpret_cast<const bf16x8*>(Bbase + (0 * 128 + ns * 16) * 512 + 0 * 32);
        bn[ns] = *reinterpret_cast<const bf16x8*>(Bbase + (0 * 128 + ns * 16) * 512 + 1 * 32);
    }

#pragma unroll
    for (int chunk = 0; chunk < 4; ++chunk) {
        f32x4 acc[4][2];
#pragma unroll
        for (int mt = 0; mt < 4; ++mt)
#pragma unroll
            for (int ns = 0; ns < 2; ++ns) acc[mt][ns] = (f32x4){0.f, 0.f, 0.f, 0.f};

#pragma unroll
        for (int ks8 = 0; ks8 < 8; ++ks8) {
            const int ks = ks8 * 2;
            // ---- half A: prefetch linear step (chunk*16+ks+2) mod 64, compute bc @ ks
            {
                const int l = (chunk * 16 + ks + 2) & 63;
                const int pc = l >> 4, pk = l & 15;
#pragma unroll
                for (int ns = 0; ns < 2; ++ns)
                    bp0[ns] = *reinterpret_cast<const bf16x8*>(
                        Bbase + (pc * 128 + ns * 16) * 512 + pk * 32);
            }
            {
                const int kc = ks * 32 + lk;
                bf16x8 a[4];
#pragma unroll
                for (int mt = 0; mt < 4; ++mt) {
                    const int m = mt * 16 + lrow;
                    const int idx = (m * 512 + kc) ^ ((m & 7) << 3);
                    a[mt] = *reinterpret_cast<const bf16x8*>(&At[idx]);
                }
#pragma unroll
                for (int mt = 0; mt < 4; ++mt)
#pragma unroll
                    for (int ns = 0; ns < 2; ++ns)
                        acc[mt][ns] = __builtin_amdgcn_mfma_f32_16x16x32_bf16(
                            a[mt], bc[ns], acc[mt][ns], 0, 0, 0);
            }
            // ---- half B: prefetch (chunk*16+ks+3) mod 64, compute bn @ ks+1
            {
                const int l = (chunk * 16 + ks + 3) & 63;
                const int pc = l >> 4, pk = l & 15;
#pragma unroll
                for (int ns = 0; ns < 2; ++ns)
                    bp1[ns] = *reinterpret_cast<const bf16x8*>(
                        Bbase + (pc * 128 + ns * 16) * 512 + pk * 32);
            }
            {
                const int kc = (ks + 1) * 32 + lk;
                bf16x8 a[4];
#pragma unroll
                for (int mt = 0; mt < 4; ++mt) {
                    const int m = mt * 16 + lrow;
                    const int idx = (m * 512 + kc) ^ ((m & 7) << 3);
                    a[mt] = *reinterpret_cast<const bf16x8*>(&At[idx]);
                }
#pragma unroll
                for (int mt = 0; mt < 4; ++mt)
#pragma unroll
                    for (int ns = 0; ns < 2; ++ns)
                        acc[mt][ns] = __builtin_amdgcn_mfma_f32_16x16x32_bf16(
                            a[mt], bn[ns], acc[mt][ns], 0, 0, 0);
            }
            // rotate
#pragma unroll
            for (int ns = 0; ns < 2; ++ns) { bc[ns] = bp0[ns]; bn[ns] = bp1[ns]; }
        }

        // epilogue for this o-chunk (overlaps the already-issued next-chunk B loads)
        const int nb = chunk * 128 + wave * 32;
#pragma unroll
        for (int ns = 0; ns < 2; ++ns) {
            const int o = nb + ns * 16 + lrow;
            const float hbv = hb[b * 512 + o];
            const float vv = v[o];
#pragma unroll
            for (int mt = 0; mt < 4; ++mt)
#pragma unroll
                for (int r = 0; r < 4; ++r) {
                    const float x = acc[mt][ns][r] + hbv;
                    score_acc[mt][r] = fmaf(fast_tanh(x), vv, score_acc[mt][r]);
                }
        }
    }

    // reduce across the 16 columns held by lanes (low 4 lane bits)
#pragma unroll
    for (int off = 1; off < 16; off <<= 1)
#pragma unroll
        for (int mt = 0; mt < 4; ++mt)
#pragma unroll
            for (int r = 0; r < 4; ++r)
                score_acc[mt][r] += __shfl_xor(score_acc[mt][r], off, 64);

    if (lrow == 0) {
        const int rbase = (lane >> 4) * 4;
#pragma unroll
        for (int mt = 0; mt < 4; ++mt)
#pragma unroll
            for (int r = 0; r < 4; ++r)
                s_red[wave][mt * 16 + rbase + r] = score_acc[mt][r];
    }
    __syncthreads();

    if (tid < 64)
        scores[(size_t)b * TT + t0 + tid] =
            s_red[0][tid] + s_red[1][tid] + s_red[2][tid] + s_red[3][tid];
}

// ---- Kernel 4: softmax over T per b
__global__ void softmax_kernel(const float* __restrict__ scores, float* __restrict__ out) {
    __shared__ float wred[4];
    __shared__ float wsum[4];
    const int b = blockIdx.x;
    const int tid = threadIdx.x;   // 256
    float vals[8];
    float mx = -1e30f;
#pragma unroll
    for (int i = 0; i < 8; ++i) {
        vals[i] = scores[b * TT + i * 256 + tid];
        mx = fmaxf(mx, vals[i]);
    }
#pragma unroll
    for (int off = 32; off; off >>= 1) mx = fmaxf(mx, __shfl_xor(mx, off, 64));
    if ((tid & 63) == 0) wred[tid >> 6] = mx;
    __syncthreads();
    mx = fmaxf(fmaxf(wred[0], wred[1]), fmaxf(wred[2], wred[3]));
    float s = 0.0f;
#pragma unroll
    for (int i = 0; i < 8; ++i) {
        vals[i] = __expf(vals[i] - mx);
        s += vals[i];
    }
#pragma unroll
    for (int off = 32; off; off >>= 1) s += __shfl_xor(s, off, 64);
    if ((tid & 63) == 0) wsum[tid >> 6] = s;
    __syncthreads();
    s = wsum[0] + wsum[1] + wsum[2] + wsum[3];
    const float inv = 1.0f / s;
#pragma unroll
    for (int i = 0; i < 8; ++i) out[b * TT + i * 256 + tid] = vals[i] * inv;
}

extern "C" void kernel_launch(void* const* d_in, const int* in_sizes, int n_in,
                              void* d_out, int out_size, void* d_ws, size_t ws_size,
                              hipStream_t stream) {
    const float* hidden = (const float*)d_in[0];   // (1,B,H)
    const float* enc    = (const float*)d_in[1];   // (T,B,H)
    const float* W      = (const float*)d_in[2];   // (H,2H)
    const float* b_attn = (const float*)d_in[3];   // (H,)
    const float* v      = (const float*)d_in[4];   // (H,)
    float* out = (float*)d_out;                    // (B,1,T)

    char* base = (char*)d_ws;
    short* W2b   = (short*)base;                       // 512*512*2 = 524288 B
    float* hb    = (float*)(base + 524288);            // 32*512*4  =  65536 B
    float* scores= (float*)(base + 524288 + 65536);    // 32*2048*4 = 262144 B

    conv_w2_kernel<<<1024, 256, 0, stream>>>(W, W2b);
    hb_kernel<<<64, 256, 0, stream>>>(hidden, W, b_attn, hb);
    attn_main_kernel<<<1024, 256, 0, stream>>>(enc, W2b, hb, v, scores);
    softmax_kernel<<<32, 256, 0, stream>>>(scores, out);
}

// Round 8
// 111.660 us; speedup vs baseline: 1.4828x; 1.2353x over previous
//
#include <hip/hip_runtime.h>
#include <hip/hip_bf16.h>

// Problem: T=2048, B=32, H=512
//   scores[b,t] = sum_o v[o] * tanh( hb[b,o] + sum_h enc[t,b,h] * W2[o,h] )
//   out[b,0,t]  = softmax_t(scores[b,:])
//
// HARD-WON RULES (R2/R3/R5/R6/R7 post-mortems):
//  - WRITE_SIZE >> 2MB == scratch spill. Rotating register prefetch arrays
//    (R2/R7) and __launch_bounds__ min-waves>=4 (R3/R5) both trigger it.
//  - Occupancy is not the lever (R6). The stall is scattered B-gathers from L2
//    inside the K-loop. Fix structurally: B through LDS via global_load_lds
//    (no registers), A reg-staged issue-early/write-late, double-buffered.
// R8: classic 128x128-tile 2-phase GEMM per cdna_hip_programming.md §5.

#define TT 2048
#define BB 32
#define HH 512

typedef __attribute__((ext_vector_type(8))) short bf16x8;
typedef __attribute__((ext_vector_type(4))) float f32x4;

static __device__ __forceinline__ unsigned cvt2(float a, float b) {
    union { __hip_bfloat162 h; unsigned u; } cv;
    cv.h = __float22bfloat162_rn(make_float2(a, b));   // v_cvt_pk_bf16_f32
    return cv.u;
}

static __device__ __forceinline__ unsigned short f2bf(float f) {
    unsigned int u = __float_as_uint(f);
    unsigned int r = (u + 0x7FFFu + ((u >> 16) & 1u)) >> 16;  // RNE
    return (unsigned short)r;
}

// tanh(x) = 1 - 2/(1+e^{2x});  inf-safe at both ends.
static __device__ __forceinline__ float fast_tanh(float x) {
    float e = __expf(2.0f * x);
    return 1.0f - 2.0f * __builtin_amdgcn_rcpf(1.0f + e);
}

static __device__ __forceinline__ void gload_lds16(const void* g, void* l) {
    __builtin_amdgcn_global_load_lds(
        (const __attribute__((address_space(1))) unsigned int*)g,
        (__attribute__((address_space(3))) unsigned int*)l, 16, 0, 0);
}

// ---- Kernel 1: pack W2 (= W_attn[:, 512:1024]) into the swizzled LDS image.
// Layout: idx = nt*65536 + ks*8192 + j*64 + c  (shorts), where the LDS tile for
// (nt,ks) is Bs[j][c] and the element stored at (j,c) is W2[nt*128+j][ks*64 + (c ^ ((j&7)<<3))].
// Then main-kernel global_load_lds with a LINEAR dest reproduces the swizzled tile.
__global__ void pack_w2_kernel(const float* __restrict__ W, short* __restrict__ W2p) {
    int idx = blockIdx.x * 256 + threadIdx.x;      // 262144 total
    int nt = idx >> 16;
    int ks = (idx >> 13) & 7;
    int s  = idx & 8191;
    int j  = s >> 6;
    int c  = s & 63;
    int kk = c ^ ((j & 7) << 3);
    int o  = nt * 128 + j;
    int k  = ks * 64 + kk;
    W2p[idx] = (short)f2bf(W[o * 1024 + 512 + k]);
}

// ---- Kernel 2: hb[b][o] = b_attn[o] + sum_h hidden[b,h] * W_attn[o,h]
__global__ void hb_kernel(const float* __restrict__ hidden, const float* __restrict__ W,
                          const float* __restrict__ b_attn, float* __restrict__ hb) {
    __shared__ float hrow[512];
    int b = blockIdx.x >> 1;
    int o = ((blockIdx.x & 1) << 8) + threadIdx.x;
    for (int h = threadIdx.x; h < 512; h += 256) hrow[h] = hidden[b * 512 + h];
    __syncthreads();
    const float4* wr = reinterpret_cast<const float4*>(W + (size_t)o * 1024);
    const float4* hr = reinterpret_cast<const float4*>(hrow);
    float acc = b_attn[o];
#pragma unroll 8
    for (int i = 0; i < 128; ++i) {
        float4 w = wr[i], h4 = hr[i];
        acc += w.x * h4.x + w.y * h4.y + w.z * h4.z + w.w * h4.w;
    }
    hb[b * 512 + o] = acc;
}

// ---- Kernel 3: 128x128-tile double-buffered GEMM + fused tanh/v-dot epilogue.
// Grid: 2048 blocks = 512 M-tiles (128 t-rows, b = mtile>>4) x 4 N-tiles (128 o-cols).
// 256 threads = 4 waves (wr x wc = 2x2), each wave computes 64x64.
// K = 512 in 8 steps of 64. A: global->reg->cvt->ds_write (swizzled).
// B: global_load_lds from pre-swizzled W2p (linear dest). One barrier per step.
__global__ __launch_bounds__(256, 2) void attn_main_kernel(
    const float* __restrict__ enc, const short* __restrict__ W2p,
    const float* __restrict__ hb, const float* __restrict__ v,
    float* __restrict__ scores_part)
{
    __shared__ short As[2][128 * 64];   // 16KB x2, swizzled: col c2 = c ^ ((r&7)<<3)
    __shared__ short Bs[2][128 * 64];   // 16KB x2, image pre-swizzled by pack kernel
    __shared__ float s_red[2][128];

    const int tid = threadIdx.x;
    const int bid = blockIdx.x;
    const int nt = bid & 3;              // N-tile (128 o-cols)
    const int mtile = bid >> 2;          // 512 M-tiles
    const int b = mtile >> 4;            // batch
    const int t0 = (mtile & 15) * 128;   // t-range base

    const int wave = tid >> 6;
    const int lane = tid & 63;
    const int wr = wave >> 1;            // row half (64 rows)
    const int wc = wave & 1;             // col half (64 cols)
    const int lcol = lane & 15;
    const int lq = lane >> 4;

    // A staging geometry: 4 passes; pass p: row r = p*32 + (tid>>3), float col (tid&7)*8
    const int arow = tid >> 3;           // 0..31
    const int afc = (tid & 7) * 8;       // 0..56
    // B staging source (shorts): + ks*8192 per step, + c*512 per call; lane offset baked in
    const short* bsrc = W2p + nt * 65536 + (wave * 4) * 512 + lane * 8;

    f32x4 acc[4][4];
#pragma unroll
    for (int mt = 0; mt < 4; ++mt)
#pragma unroll
        for (int ns = 0; ns < 4; ++ns) acc[mt][ns] = (f32x4){0.f, 0.f, 0.f, 0.f};

    float4 rA[8];

#define A_LOAD(KS)                                                                  \
    {                                                                               \
        _Pragma("unroll")                                                           \
        for (int p = 0; p < 4; ++p) {                                               \
            const int r = p * 32 + arow;                                            \
            const float* src = enc + ((size_t)(t0 + r) * BB + b) * HH + (KS) * 64 + afc; \
            rA[p * 2]     = *reinterpret_cast<const float4*>(src);                  \
            rA[p * 2 + 1] = *reinterpret_cast<const float4*>(src + 4);              \
        }                                                                           \
    }

#define B_STAGE(KS, BUF)                                                            \
    {                                                                               \
        const short* s0 = bsrc + (KS) * 8192;                                       \
        _Pragma("unroll")                                                           \
        for (int c = 0; c < 4; ++c)                                                 \
            gload_lds16(s0 + c * 512, &Bs[BUF][(wave * 4 + c) * 512]);              \
    }

#define A_WRITE(BUF)                                                                \
    {                                                                               \
        _Pragma("unroll")                                                           \
        for (int p = 0; p < 4; ++p) {                                               \
            const int r = p * 32 + arow;                                            \
            uint4 pk;                                                               \
            pk.x = cvt2(rA[p * 2].x, rA[p * 2].y);                                  \
            pk.y = cvt2(rA[p * 2].z, rA[p * 2].w);                                  \
            pk.z = cvt2(rA[p * 2 + 1].x, rA[p * 2 + 1].y);                          \
            pk.w = cvt2(rA[p * 2 + 1].z, rA[p * 2 + 1].w);                          \
            const int cs = afc ^ ((r & 7) << 3);                                    \
            *reinterpret_cast<uint4*>(&As[BUF][r * 64 + cs]) = pk;                  \
        }                                                                           \
    }

#define COMPUTE(BUF)                                                                \
    {                                                                               \
        _Pragma("unroll")                                                           \
        for (int ksub = 0; ksub < 2; ++ksub) {                                      \
            const int kk = ksub * 32 + lq * 8;                                      \
            bf16x8 af[4], bfr[4];                                                   \
            _Pragma("unroll")                                                       \
            for (int mt = 0; mt < 4; ++mt) {                                        \
                const int r = wr * 64 + mt * 16 + lcol;                             \
                af[mt] = *reinterpret_cast<const bf16x8*>(                          \
                    &As[BUF][r * 64 + (kk ^ ((r & 7) << 3))]);                      \
            }                                                                       \
            _Pragma("unroll")                                                       \
            for (int ns = 0; ns < 4; ++ns) {                                        \
                const int j = wc * 64 + ns * 16 + lcol;                             \
                bfr[ns] = *reinterpret_cast<const bf16x8*>(                         \
                    &Bs[BUF][j * 64 + (kk ^ ((j & 7) << 3))]);                      \
            }                                                                       \
            _Pragma("unroll")                                                       \
            for (int mt = 0; mt < 4; ++mt)                                          \
                _Pragma("unroll")                                                   \
                for (int ns = 0; ns < 4; ++ns)                                      \
                    acc[mt][ns] = __builtin_amdgcn_mfma_f32_16x16x32_bf16(          \
                        af[mt], bfr[ns], acc[mt][ns], 0, 0, 0);                     \
        }                                                                           \
    }

    // ---- prologue: stage step 0 into buf 0
    A_LOAD(0);
    B_STAGE(0, 0);
    A_WRITE(0);          // compiler inserts vmcnt waits for rA
    __syncthreads();     // drains gload_lds (compiler emits vmcnt(0) before barrier)

    // ---- main K-loop: one barrier per step, issue-early / write-late
    for (int ks = 0; ks < 8; ++ks) {
        const int cur = ks & 1;
        if (ks < 7) {
            A_LOAD(ks + 1);        // issue global loads early (hide under MFMA)
            B_STAGE(ks + 1, cur ^ 1);
        }
        COMPUTE(cur);
        if (ks < 7) {
            A_WRITE(cur ^ 1);      // cvt + ds_write after compute
            __syncthreads();
        }
    }

    // ---- epilogue: tanh + v-dot, reduce over this block's 128 cols
    float part[4][4];
#pragma unroll
    for (int mt = 0; mt < 4; ++mt)
#pragma unroll
        for (int j = 0; j < 4; ++j) part[mt][j] = 0.0f;

#pragma unroll
    for (int ns = 0; ns < 4; ++ns) {
        const int o = nt * 128 + wc * 64 + ns * 16 + lcol;
        const float hbv = hb[b * 512 + o];
        const float vv = v[o];
#pragma unroll
        for (int mt = 0; mt < 4; ++mt)
#pragma unroll
            for (int j = 0; j < 4; ++j)
                part[mt][j] = fmaf(fast_tanh(acc[mt][ns][j] + hbv), vv, part[mt][j]);
    }

#pragma unroll
    for (int off = 1; off < 16; off <<= 1)
#pragma unroll
        for (int mt = 0; mt < 4; ++mt)
#pragma unroll
            for (int j = 0; j < 4; ++j)
                part[mt][j] += __shfl_xor(part[mt][j], off, 64);

    if (lcol == 0) {
#pragma unroll
        for (int mt = 0; mt < 4; ++mt)
#pragma unroll
            for (int j = 0; j < 4; ++j)
                s_red[wc][wr * 64 + mt * 16 + lq * 4 + j] = part[mt][j];
    }
    __syncthreads();

    if (tid < 128)
        scores_part[((size_t)nt * BB + b) * TT + t0 + tid] =
            s_red[0][tid] + s_red[1][tid];
}

// ---- Kernel 4: sum 4 N-tile partials + softmax over T per b
__global__ void softmax_kernel(const float* __restrict__ sp, float* __restrict__ out) {
    __shared__ float wred[4];
    __shared__ float wsum[4];
    const int b = blockIdx.x;
    const int tid = threadIdx.x;   // 256
    float vals[8];
    float mx = -1e30f;
#pragma unroll
    for (int i = 0; i < 8; ++i) {
        const int t = i * 256 + tid;
        const float s = sp[(size_t)b * TT + t] + sp[((size_t)BB + b) * TT + t] +
                        sp[((size_t)2 * BB + b) * TT + t] + sp[((size_t)3 * BB + b) * TT + t];
        vals[i] = s;
        mx = fmaxf(mx, s);
    }
#pragma unroll
    for (int off = 32; off; off >>= 1) mx = fmaxf(mx, __shfl_xor(mx, off, 64));
    if ((tid & 63) == 0) wred[tid >> 6] = mx;
    __syncthreads();
    mx = fmaxf(fmaxf(wred[0], wred[1]), fmaxf(wred[2], wred[3]));
    float s = 0.0f;
#pragma unroll
    for (int i = 0; i < 8; ++i) {
        vals[i] = __expf(vals[i] - mx);
        s += vals[i];
    }
#pragma unroll
    for (int off = 32; off; off >>= 1) s += __shfl_xor(s, off, 64);
    if ((tid & 63) == 0) wsum[tid >> 6] = s;
    __syncthreads();
    s = wsum[0] + wsum[1] + wsum[2] + wsum[3];
    const float inv = 1.0f / s;
#pragma unroll
    for (int i = 0; i < 8; ++i) out[b * TT + i * 256 + tid] = vals[i] * inv;
}

extern "C" void kernel_launch(void* const* d_in, const int* in_sizes, int n_in,
                              void* d_out, int out_size, void* d_ws, size_t ws_size,
                              hipStream_t stream) {
    const float* hidden = (const float*)d_in[0];   // (1,B,H)
    const float* enc    = (const float*)d_in[1];   // (T,B,H)
    const float* W      = (const float*)d_in[2];   // (H,2H)
    const float* b_attn = (const float*)d_in[3];   // (H,)
    const float* v      = (const float*)d_in[4];   // (H,)
    float* out = (float*)d_out;                    // (B,1,T)

    char* base = (char*)d_ws;
    short* W2p = (short*)base;                          // 512*512*2 = 524288 B
    float* hb  = (float*)(base + 524288);               // 32*512*4  =  65536 B
    float* sp  = (float*)(base + 524288 + 65536);       // 4*32*2048*4 = 1048576 B

    pack_w2_kernel<<<1024, 256, 0, stream>>>(W, W2p);
    hb_kernel<<<64, 256, 0, stream>>>(hidden, W, b_attn, hb);
    attn_main_kernel<<<2048, 256, 0, stream>>>(enc, W2p, hb, v, sp);
    softmax_kernel<<<32, 256, 0, stream>>>(sp, out);
}

// Round 9
// 89.847 us; speedup vs baseline: 1.8427x; 1.2428x over previous
//
#include <hip/hip_runtime.h>
#include <hip/hip_bf16.h>

// Problem: T=2048, B=32, H=512
//   scores[b,t] = sum_o v[o] * tanh( hb[b,o] + sum_h enc[t,b,h] * W2[o,h] )
//   out[b,0,t]  = softmax_t(scores[b,:])
//
// HARD-WON RULES (R2/R3/R5/R6/R7 post-mortems):
//  - WRITE_SIZE >> 2MB == scratch spill. Rotating register prefetch arrays
//    (R2/R7) and __launch_bounds__ min-waves>=4 (R3/R5) both trigger it.
//  - Occupancy is not the lever (R6). Structure is: B via global_load_lds
//    (no regs), A reg-staged issue-early/write-late, double-buffered (R8 win:
//    110us, 0 bank conflicts, 0 spill).
// R9: single change vs R8 — XCD-aware remap so the 4 nt-blocks of each mtile
// run consecutively on ONE XCD (enc tile L2-resident, FETCH 264->~140MB).

#define TT 2048
#define BB 32
#define HH 512

typedef __attribute__((ext_vector_type(8))) short bf16x8;
typedef __attribute__((ext_vector_type(4))) float f32x4;

static __device__ __forceinline__ unsigned cvt2(float a, float b) {
    union { __hip_bfloat162 h; unsigned u; } cv;
    cv.h = __float22bfloat162_rn(make_float2(a, b));   // v_cvt_pk_bf16_f32
    return cv.u;
}

static __device__ __forceinline__ unsigned short f2bf(float f) {
    unsigned int u = __float_as_uint(f);
    unsigned int r = (u + 0x7FFFu + ((u >> 16) & 1u)) >> 16;  // RNE
    return (unsigned short)r;
}

// tanh(x) = 1 - 2/(1+e^{2x});  inf-safe at both ends.
static __device__ __forceinline__ float fast_tanh(float x) {
    float e = __expf(2.0f * x);
    return 1.0f - 2.0f * __builtin_amdgcn_rcpf(1.0f + e);
}

static __device__ __forceinline__ void gload_lds16(const void* g, void* l) {
    __builtin_amdgcn_global_load_lds(
        (const __attribute__((address_space(1))) unsigned int*)g,
        (__attribute__((address_space(3))) unsigned int*)l, 16, 0, 0);
}

// ---- Kernel 1: pack W2 (= W_attn[:, 512:1024]) into the swizzled LDS image.
// idx = nt*65536 + ks*8192 + j*64 + c (shorts); element = W2[nt*128+j][ks*64 + (c ^ ((j&7)<<3))]
__global__ void pack_w2_kernel(const float* __restrict__ W, short* __restrict__ W2p) {
    int idx = blockIdx.x * 256 + threadIdx.x;      // 262144 total
    int nt = idx >> 16;
    int ks = (idx >> 13) & 7;
    int s  = idx & 8191;
    int j  = s >> 6;
    int c  = s & 63;
    int kk = c ^ ((j & 7) << 3);
    int o  = nt * 128 + j;
    int k  = ks * 64 + kk;
    W2p[idx] = (short)f2bf(W[o * 1024 + 512 + k]);
}

// ---- Kernel 2: hb[b][o] = b_attn[o] + sum_h hidden[b,h] * W_attn[o,h]
__global__ void hb_kernel(const float* __restrict__ hidden, const float* __restrict__ W,
                          const float* __restrict__ b_attn, float* __restrict__ hb) {
    __shared__ float hrow[512];
    int b = blockIdx.x >> 1;
    int o = ((blockIdx.x & 1) << 8) + threadIdx.x;
    for (int h = threadIdx.x; h < 512; h += 256) hrow[h] = hidden[b * 512 + h];
    __syncthreads();
    const float4* wr = reinterpret_cast<const float4*>(W + (size_t)o * 1024);
    const float4* hr = reinterpret_cast<const float4*>(hrow);
    float acc = b_attn[o];
#pragma unroll 8
    for (int i = 0; i < 128; ++i) {
        float4 w = wr[i], h4 = hr[i];
        acc += w.x * h4.x + w.y * h4.y + w.z * h4.z + w.w * h4.w;
    }
    hb[b * 512 + o] = acc;
}

// ---- Kernel 3: 128x128-tile double-buffered GEMM + fused tanh/v-dot epilogue.
// Grid: 2048 blocks. XCD-remap: xcd=bid&7, idx=bid>>3, w=xcd*256+idx;
// nt=w&3, mtile=w>>2 — the 4 nt-blocks of an mtile are consecutive on one XCD.
// 256 threads = 4 waves (wr x wc = 2x2), each wave computes 64x64.
// K = 512 in 8 steps of 64. A: global->reg->cvt->ds_write (swizzled).
// B: global_load_lds from pre-swizzled W2p (linear dest). One barrier per step.
__global__ __launch_bounds__(256, 2) void attn_main_kernel(
    const float* __restrict__ enc, const short* __restrict__ W2p,
    const float* __restrict__ hb, const float* __restrict__ v,
    float* __restrict__ scores_part)
{
    __shared__ short As[2][128 * 64];   // 16KB x2, swizzled: col c2 = c ^ ((r&7)<<3)
    __shared__ short Bs[2][128 * 64];   // 16KB x2, image pre-swizzled by pack kernel
    __shared__ float s_red[2][128];

    const int tid = threadIdx.x;
    const int bid = blockIdx.x;
    const int w = (bid & 7) * 256 + (bid >> 3);  // XCD-contiguous work id (bijective)
    const int nt = w & 3;                // N-tile (128 o-cols)
    const int mtile = w >> 2;            // 512 M-tiles
    const int b = mtile >> 4;            // batch
    const int t0 = (mtile & 15) * 128;   // t-range base

    const int wave = tid >> 6;
    const int lane = tid & 63;
    const int wr = wave >> 1;            // row half (64 rows)
    const int wc = wave & 1;             // col half (64 cols)
    const int lcol = lane & 15;
    const int lq = lane >> 4;

    // A staging geometry: 4 passes; pass p: row r = p*32 + (tid>>3), float col (tid&7)*8
    const int arow = tid >> 3;           // 0..31
    const int afc = (tid & 7) * 8;       // 0..56
    // B staging source (shorts): + ks*8192 per step, + c*512 per call; lane offset baked in
    const short* bsrc = W2p + nt * 65536 + (wave * 4) * 512 + lane * 8;

    f32x4 acc[4][4];
#pragma unroll
    for (int mt = 0; mt < 4; ++mt)
#pragma unroll
        for (int ns = 0; ns < 4; ++ns) acc[mt][ns] = (f32x4){0.f, 0.f, 0.f, 0.f};

    float4 rA[8];

#define A_LOAD(KS)                                                                  \
    {                                                                               \
        _Pragma("unroll")                                                           \
        for (int p = 0; p < 4; ++p) {                                               \
            const int r = p * 32 + arow;                                            \
            const float* src = enc + ((size_t)(t0 + r) * BB + b) * HH + (KS) * 64 + afc; \
            rA[p * 2]     = *reinterpret_cast<const float4*>(src);                  \
            rA[p * 2 + 1] = *reinterpret_cast<const float4*>(src + 4);              \
        }                                                                           \
    }

#define B_STAGE(KS, BUF)                                                            \
    {                                                                               \
        const short* s0 = bsrc + (KS) * 8192;                                       \
        _Pragma("unroll")                                                           \
        for (int c = 0; c < 4; ++c)                                                 \
            gload_lds16(s0 + c * 512, &Bs[BUF][(wave * 4 + c) * 512]);              \
    }

#define A_WRITE(BUF)                                                                \
    {                                                                               \
        _Pragma("unroll")                                                           \
        for (int p = 0; p < 4; ++p) {                                               \
            const int r = p * 32 + arow;                                            \
            uint4 pk;                                                               \
            pk.x = cvt2(rA[p * 2].x, rA[p * 2].y);                                  \
            pk.y = cvt2(rA[p * 2].z, rA[p * 2].w);                                  \
            pk.z = cvt2(rA[p * 2 + 1].x, rA[p * 2 + 1].y);                          \
            pk.w = cvt2(rA[p * 2 + 1].z, rA[p * 2 + 1].w);                          \
            const int cs = afc ^ ((r & 7) << 3);                                    \
            *reinterpret_cast<uint4*>(&As[BUF][r * 64 + cs]) = pk;                  \
        }                                                                           \
    }

#define COMPUTE(BUF)                                                                \
    {                                                                               \
        _Pragma("unroll")                                                           \
        for (int ksub = 0; ksub < 2; ++ksub) {                                      \
            const int kk = ksub * 32 + lq * 8;                                      \
            bf16x8 af[4], bfr[4];                                                   \
            _Pragma("unroll")                                                       \
            for (int mt = 0; mt < 4; ++mt) {                                        \
                const int r = wr * 64 + mt * 16 + lcol;                             \
                af[mt] = *reinterpret_cast<const bf16x8*>(                          \
                    &As[BUF][r * 64 + (kk ^ ((r & 7) << 3))]);                      \
            }                                                                       \
            _Pragma("unroll")                                                       \
            for (int ns = 0; ns < 4; ++ns) {                                        \
                const int j = wc * 64 + ns * 16 + lcol;                             \
                bfr[ns] = *reinterpret_cast<const bf16x8*>(                         \
                    &Bs[BUF][j * 64 + (kk ^ ((j & 7) << 3))]);                      \
            }                                                                       \
            _Pragma("unroll")                                                       \
            for (int mt = 0; mt < 4; ++mt)                                          \
                _Pragma("unroll")                                                   \
                for (int ns = 0; ns < 4; ++ns)                                      \
                    acc[mt][ns] = __builtin_amdgcn_mfma_f32_16x16x32_bf16(          \
                        af[mt], bfr[ns], acc[mt][ns], 0, 0, 0);                     \
        }                                                                           \
    }

    // ---- prologue: stage step 0 into buf 0
    A_LOAD(0);
    B_STAGE(0, 0);
    A_WRITE(0);          // compiler inserts vmcnt waits for rA
    __syncthreads();     // drains gload_lds (compiler emits vmcnt(0) before barrier)

    // ---- main K-loop: one barrier per step, issue-early / write-late
    for (int ks = 0; ks < 8; ++ks) {
        const int cur = ks & 1;
        if (ks < 7) {
            A_LOAD(ks + 1);        // issue global loads early (hide under MFMA)
            B_STAGE(ks + 1, cur ^ 1);
        }
        COMPUTE(cur);
        if (ks < 7) {
            A_WRITE(cur ^ 1);      // cvt + ds_write after compute
            __syncthreads();
        }
    }

    // ---- epilogue: tanh + v-dot, reduce over this block's 128 cols
    float part[4][4];
#pragma unroll
    for (int mt = 0; mt < 4; ++mt)
#pragma unroll
        for (int j = 0; j < 4; ++j) part[mt][j] = 0.0f;

#pragma unroll
    for (int ns = 0; ns < 4; ++ns) {
        const int o = nt * 128 + wc * 64 + ns * 16 + lcol;
        const float hbv = hb[b * 512 + o];
        const float vv = v[o];
#pragma unroll
        for (int mt = 0; mt < 4; ++mt)
#pragma unroll
            for (int j = 0; j < 4; ++j)
                part[mt][j] = fmaf(fast_tanh(acc[mt][ns][j] + hbv), vv, part[mt][j]);
    }

#pragma unroll
    for (int off = 1; off < 16; off <<= 1)
#pragma unroll
        for (int mt = 0; mt < 4; ++mt)
#pragma unroll
            for (int j = 0; j < 4; ++j)
                part[mt][j] += __shfl_xor(part[mt][j], off, 64);

    if (lcol == 0) {
#pragma unroll
        for (int mt = 0; mt < 4; ++mt)
#pragma unroll
            for (int j = 0; j < 4; ++j)
                s_red[wc][wr * 64 + mt * 16 + lq * 4 + j] = part[mt][j];
    }
    __syncthreads();

    if (tid < 128)
        scores_part[((size_t)nt * BB + b) * TT + t0 + tid] =
            s_red[0][tid] + s_red[1][tid];
}

// ---- Kernel 4: sum 4 N-tile partials + softmax over T per b
__global__ void softmax_kernel(const float* __restrict__ sp, float* __restrict__ out) {
    __shared__ float wred[4];
    __shared__ float wsum[4];
    const int b = blockIdx.x;
    const int tid = threadIdx.x;   // 256
    float vals[8];
    float mx = -1e30f;
#pragma unroll
    for (int i = 0; i < 8; ++i) {
        const int t = i * 256 + tid;
        const float s = sp[(size_t)b * TT + t] + sp[((size_t)BB + b) * TT + t] +
                        sp[((size_t)2 * BB + b) * TT + t] + sp[((size_t)3 * BB + b) * TT + t];
        vals[i] = s;
        mx = fmaxf(mx, s);
    }
#pragma unroll
    for (int off = 32; off; off >>= 1) mx = fmaxf(mx, __shfl_xor(mx, off, 64));
    if ((tid & 63) == 0) wred[tid >> 6] = mx;
    __syncthreads();
    mx = fmaxf(fmaxf(wred[0], wred[1]), fmaxf(wred[2], wred[3]));
    float s = 0.0f;
#pragma unroll
    for (int i = 0; i < 8; ++i) {
        vals[i] = __expf(vals[i] - mx);
        s += vals[i];
    }
#pragma unroll
    for (int off = 32; off; off >>= 1) s += __shfl_xor(s, off, 64);
    if ((tid & 63) == 0) wsum[tid >> 6] = s;
    __syncthreads();
    s = wsum[0] + wsum[1] + wsum[2] + wsum[3];
    const float inv = 1.0f / s;
#pragma unroll
    for (int i = 0; i < 8; ++i) out[b * TT + i * 256 + tid] = vals[i] * inv;
}

extern "C" void kernel_launch(void* const* d_in, const int* in_sizes, int n_in,
                              void* d_out, int out_size, void* d_ws, size_t ws_size,
                              hipStream_t stream) {
    const float* hidden = (const float*)d_in[0];   // (1,B,H)
    const float* enc    = (const float*)d_in[1];   // (T,B,H)
    const float* W      = (const float*)d_in[2];   // (H,2H)
    const float* b_attn = (const float*)d_in[3];   // (H,)
    const float* v      = (const float*)d_in[4];   // (H,)
    float* out = (float*)d_out;                    // (B,1,T)

    char* base = (char*)d_ws;
    short* W2p = (short*)base;                          // 512*512*2 = 524288 B
    float* hb  = (float*)(base + 524288);               // 32*512*4  =  65536 B
    float* sp  = (float*)(base + 524288 + 65536);       // 4*32*2048*4 = 1048576 B

    pack_w2_kernel<<<1024, 256, 0, stream>>>(W, W2p);
    hb_kernel<<<64, 256, 0, stream>>>(hidden, W, b_attn, hb);
    attn_main_kernel<<<2048, 256, 0, stream>>>(enc, W2p, hb, v, sp);
    softmax_kernel<<<32, 256, 0, stream>>>(sp, out);
}

// Round 10
// 83.494 us; speedup vs baseline: 1.9829x; 1.0761x over previous
//
#include <hip/hip_runtime.h>
#include <hip/hip_bf16.h>

// Problem: T=2048, B=32, H=512
//   scores[b,t] = sum_o v[o] * tanh( hb[b,o] + sum_h enc[t,b,h] * W2[o,h] )
//   out[b,0,t]  = softmax_t(scores[b,:])
//
// HARD-WON RULES (R2..R9 post-mortems):
//  - WRITE_SIZE >> 2MB == scratch spill. Rotating/indexed register arrays and
//    __launch_bounds__ min-waves>=4 trigger it. Keep staging code fully static.
//  - R8 structure (B via global_load_lds from pre-swizzled image, A reg-staged,
//    double-buffered, 0 bank conflicts) + R9 XCD remap (FETCH 264->71MB) are
//    verified good. Keep.
//  - R9 residual: per-step wall ~2300cyc vs ~600 of work — A_LOAD(ks+1) gets
//    only 1 COMPUTE of latency cover. R10: A-prefetch distance 2 (rA0/rA1
//    static ping-pong, load at s-2, LDS-write at s-1, compute at s).

#define TT 2048
#define BB 32
#define HH 512

typedef __attribute__((ext_vector_type(8))) short bf16x8;
typedef __attribute__((ext_vector_type(4))) float f32x4;

static __device__ __forceinline__ unsigned cvt2(float a, float b) {
    union { __hip_bfloat162 h; unsigned u; } cv;
    cv.h = __float22bfloat162_rn(make_float2(a, b));   // v_cvt_pk_bf16_f32
    return cv.u;
}

static __device__ __forceinline__ unsigned short f2bf(float f) {
    unsigned int u = __float_as_uint(f);
    unsigned int r = (u + 0x7FFFu + ((u >> 16) & 1u)) >> 16;  // RNE
    return (unsigned short)r;
}

// tanh(x) = 1 - 2/(1+e^{2x});  inf-safe at both ends.
static __device__ __forceinline__ float fast_tanh(float x) {
    float e = __expf(2.0f * x);
    return 1.0f - 2.0f * __builtin_amdgcn_rcpf(1.0f + e);
}

static __device__ __forceinline__ void gload_lds16(const void* g, void* l) {
    __builtin_amdgcn_global_load_lds(
        (const __attribute__((address_space(1))) unsigned int*)g,
        (__attribute__((address_space(3))) unsigned int*)l, 16, 0, 0);
}

// ---- Kernel 1: pack W2 (= W_attn[:, 512:1024]) into the swizzled LDS image.
// idx = nt*65536 + ks*8192 + j*64 + c (shorts); element = W2[nt*128+j][ks*64 + (c ^ ((j&7)<<3))]
__global__ void pack_w2_kernel(const float* __restrict__ W, short* __restrict__ W2p) {
    int idx = blockIdx.x * 256 + threadIdx.x;      // 262144 total
    int nt = idx >> 16;
    int ks = (idx >> 13) & 7;
    int s  = idx & 8191;
    int j  = s >> 6;
    int c  = s & 63;
    int kk = c ^ ((j & 7) << 3);
    int o  = nt * 128 + j;
    int k  = ks * 64 + kk;
    W2p[idx] = (short)f2bf(W[o * 1024 + 512 + k]);
}

// ---- Kernel 2: hb[b][o] = b_attn[o] + sum_h hidden[b,h] * W_attn[o,h]
__global__ void hb_kernel(const float* __restrict__ hidden, const float* __restrict__ W,
                          const float* __restrict__ b_attn, float* __restrict__ hb) {
    __shared__ float hrow[512];
    int b = blockIdx.x >> 1;
    int o = ((blockIdx.x & 1) << 8) + threadIdx.x;
    for (int h = threadIdx.x; h < 512; h += 256) hrow[h] = hidden[b * 512 + h];
    __syncthreads();
    const float4* wr = reinterpret_cast<const float4*>(W + (size_t)o * 1024);
    const float4* hr = reinterpret_cast<const float4*>(hrow);
    float acc = b_attn[o];
#pragma unroll 8
    for (int i = 0; i < 128; ++i) {
        float4 w = wr[i], h4 = hr[i];
        acc += w.x * h4.x + w.y * h4.y + w.z * h4.z + w.w * h4.w;
    }
    hb[b * 512 + o] = acc;
}

// ---- Kernel 3: 128x128-tile double-buffered GEMM + fused tanh/v-dot epilogue.
// Grid: 2048 blocks, XCD remap w=(bid&7)*256+(bid>>3); nt=w&3, mtile=w>>2.
// 256 threads = 4 waves (wr x wc = 2x2), each wave computes 64x64.
// K = 512 in 8 steps of 64. A: dist-2 reg prefetch (rA0/rA1) -> cvt -> ds_write.
// B: global_load_lds from pre-swizzled W2p, 1-ahead. One barrier per step.
__global__ __launch_bounds__(256, 2) void attn_main_kernel(
    const float* __restrict__ enc, const short* __restrict__ W2p,
    const float* __restrict__ hb, const float* __restrict__ v,
    float* __restrict__ scores_part)
{
    __shared__ short As[2][128 * 64];   // 16KB x2, swizzled: col c2 = c ^ ((r&7)<<3)
    __shared__ short Bs[2][128 * 64];   // 16KB x2, image pre-swizzled by pack kernel
    __shared__ float s_red[2][128];

    const int tid = threadIdx.x;
    const int bid = blockIdx.x;
    const int w = (bid & 7) * 256 + (bid >> 3);  // XCD-contiguous work id (bijective)
    const int nt = w & 3;                // N-tile (128 o-cols)
    const int mtile = w >> 2;            // 512 M-tiles
    const int b = mtile >> 4;            // batch
    const int t0 = (mtile & 15) * 128;   // t-range base

    const int wave = tid >> 6;
    const int lane = tid & 63;
    const int wr = wave >> 1;            // row half (64 rows)
    const int wc = wave & 1;             // col half (64 cols)
    const int lcol = lane & 15;
    const int lq = lane >> 4;

    // A staging geometry: pass p: row r = p*32 + (tid>>3), float col (tid&7)*8
    const int arow = tid >> 3;           // 0..31
    const int afc = (tid & 7) * 8;       // 0..56
    const float* encbase = enc + ((size_t)(t0 + arow) * BB + b) * HH + afc;
    // B staging source (shorts): + ks*8192 per step; lane offset baked in
    const short* bsrc = W2p + nt * 65536 + (wave * 4) * 512 + lane * 8;

    f32x4 acc[4][4];
#pragma unroll
    for (int mt = 0; mt < 4; ++mt)
#pragma unroll
        for (int ns = 0; ns < 4; ++ns) acc[mt][ns] = (f32x4){0.f, 0.f, 0.f, 0.f};

    float4 rA0[8], rA1[8];

#define A_LOAD(RA, KS)                                                              \
    {                                                                               \
        _Pragma("unroll")                                                           \
        for (int p = 0; p < 4; ++p) {                                               \
            const float* src = encbase + (size_t)p * 32 * BB * HH + (KS) * 64;      \
            RA[p * 2]     = *reinterpret_cast<const float4*>(src);                  \
            RA[p * 2 + 1] = *reinterpret_cast<const float4*>(src + 4);              \
        }                                                                           \
    }

#define B_STAGE(KS, BUF)                                                            \
    {                                                                               \
        const short* s0 = bsrc + (KS) * 8192;                                       \
        _Pragma("unroll")                                                           \
        for (int c = 0; c < 4; ++c)                                                 \
            gload_lds16(s0 + c * 512, &Bs[BUF][(wave * 4 + c) * 512]);              \
    }

#define A_WRITE(RA, BUF)                                                            \
    {                                                                               \
        _Pragma("unroll")                                                           \
        for (int p = 0; p < 4; ++p) {                                               \
            const int r = p * 32 + arow;                                            \
            uint4 pk;                                                               \
            pk.x = cvt2(RA[p * 2].x, RA[p * 2].y);                                  \
            pk.y = cvt2(RA[p * 2].z, RA[p * 2].w);                                  \
            pk.z = cvt2(RA[p * 2 + 1].x, RA[p * 2 + 1].y);                          \
            pk.w = cvt2(RA[p * 2 + 1].z, RA[p * 2 + 1].w);                          \
            const int cs = afc ^ ((r & 7) << 3);                                    \
            *reinterpret_cast<uint4*>(&As[BUF][r * 64 + cs]) = pk;                  \
        }                                                                           \
    }

#define COMPUTE(BUF)                                                                \
    {                                                                               \
        _Pragma("unroll")                                                           \
        for (int ksub = 0; ksub < 2; ++ksub) {                                      \
            const int kk = ksub * 32 + lq * 8;                                      \
            bf16x8 af[4], bfr[4];                                                   \
            _Pragma("unroll")                                                       \
            for (int mt = 0; mt < 4; ++mt) {                                        \
                const int r = wr * 64 + mt * 16 + lcol;                             \
                af[mt] = *reinterpret_cast<const bf16x8*>(                          \
                    &As[BUF][r * 64 + (kk ^ ((r & 7) << 3))]);                      \
            }                                                                       \
            _Pragma("unroll")                                                       \
            for (int ns = 0; ns < 4; ++ns) {                                        \
                const int j = wc * 64 + ns * 16 + lcol;                             \
                bfr[ns] = *reinterpret_cast<const bf16x8*>(                         \
                    &Bs[BUF][j * 64 + (kk ^ ((j & 7) << 3))]);                      \
            }                                                                       \
            _Pragma("unroll")                                                       \
            for (int mt = 0; mt < 4; ++mt)                                          \
                _Pragma("unroll")                                                   \
                for (int ns = 0; ns < 4; ++ns)                                      \
                    acc[mt][ns] = __builtin_amdgcn_mfma_f32_16x16x32_bf16(          \
                        af[mt], bfr[ns], acc[mt][ns], 0, 0, 0);                     \
        }                                                                           \
    }

    // ---- prologue: stage step 0; preload step 1 into rA1
    A_LOAD(rA0, 0);
    B_STAGE(0, 0);
    A_WRITE(rA0, 0);     // vmcnt stall here only (prologue)
    A_LOAD(rA1, 1);
    __syncthreads();     // drains gload_lds for step 0

    // ---- main K-loop: 8 steps, hand-unrolled x2, static ping-pong.
    // Data for step s: loaded at s-2 (rA_{s&1}), LDS-written at s-1, computed at s.
#pragma unroll
    for (int s2 = 0; s2 < 4; ++s2) {
        const int s = s2 * 2;
        // ---- even step s: compute buf0
        if (s + 2 < 8) A_LOAD(rA0, s + 2);
        B_STAGE(s + 1, 1);
        COMPUTE(0);
        A_WRITE(rA1, 1);                    // data for step s+1 (loaded at s-1)
        __syncthreads();
        // ---- odd step s+1: compute buf1
        if (s + 3 < 8) A_LOAD(rA1, s + 3);
        if (s + 2 < 8) B_STAGE(s + 2, 0);
        COMPUTE(1);
        if (s + 2 < 8) {
            A_WRITE(rA0, 0);                // data for step s+2 (loaded at s)
            __syncthreads();
        }
    }

    // ---- epilogue: tanh + v-dot, reduce over this block's 128 cols
    float part[4][4];
#pragma unroll
    for (int mt = 0; mt < 4; ++mt)
#pragma unroll
        for (int j = 0; j < 4; ++j) part[mt][j] = 0.0f;

#pragma unroll
    for (int ns = 0; ns < 4; ++ns) {
        const int o = nt * 128 + wc * 64 + ns * 16 + lcol;
        const float hbv = hb[b * 512 + o];
        const float vv = v[o];
#pragma unroll
        for (int mt = 0; mt < 4; ++mt)
#pragma unroll
            for (int j = 0; j < 4; ++j)
                part[mt][j] = fmaf(fast_tanh(acc[mt][ns][j] + hbv), vv, part[mt][j]);
    }

#pragma unroll
    for (int off = 1; off < 16; off <<= 1)
#pragma unroll
        for (int mt = 0; mt < 4; ++mt)
#pragma unroll
            for (int j = 0; j < 4; ++j)
                part[mt][j] += __shfl_xor(part[mt][j], off, 64);

    if (lcol == 0) {
#pragma unroll
        for (int mt = 0; mt < 4; ++mt)
#pragma unroll
            for (int j = 0; j < 4; ++j)
                s_red[wc][wr * 64 + mt * 16 + lq * 4 + j] = part[mt][j];
    }
    __syncthreads();

    if (tid < 128)
        scores_part[((size_t)nt * BB + b) * TT + t0 + tid] =
            s_red[0][tid] + s_red[1][tid];
}

// ---- Kernel 4: sum 4 N-tile partials + softmax over T per b
__global__ void softmax_kernel(const float* __restrict__ sp, float* __restrict__ out) {
    __shared__ float wred[4];
    __shared__ float wsum[4];
    const int b = blockIdx.x;
    const int tid = threadIdx.x;   // 256
    float vals[8];
    float mx = -1e30f;
#pragma unroll
    for (int i = 0; i < 8; ++i) {
        const int t = i * 256 + tid;
        const float s = sp[(size_t)b * TT + t] + sp[((size_t)BB + b) * TT + t] +
                        sp[((size_t)2 * BB + b) * TT + t] + sp[((size_t)3 * BB + b) * TT + t];
        vals[i] = s;
        mx = fmaxf(mx, s);
    }
#pragma unroll
    for (int off = 32; off; off >>= 1) mx = fmaxf(mx, __shfl_xor(mx, off, 64));
    if ((tid & 63) == 0) wred[tid >> 6] = mx;
    __syncthreads();
    mx = fmaxf(fmaxf(wred[0], wred[1]), fmaxf(wred[2], wred[3]));
    float s = 0.0f;
#pragma unroll
    for (int i = 0; i < 8; ++i) {
        vals[i] = __expf(vals[i] - mx);
        s += vals[i];
    }
#pragma unroll
    for (int off = 32; off; off >>= 1) s += __shfl_xor(s, off, 64);
    if ((tid & 63) == 0) wsum[tid >> 6] = s;
    __syncthreads();
    s = wsum[0] + wsum[1] + wsum[2] + wsum[3];
    const float inv = 1.0f / s;
#pragma unroll
    for (int i = 0; i < 8; ++i) out[b * TT + i * 256 + tid] = vals[i] * inv;
}

extern "C" void kernel_launch(void* const* d_in, const int* in_sizes, int n_in,
                              void* d_out, int out_size, void* d_ws, size_t ws_size,
                              hipStream_t stream) {
    const float* hidden = (const float*)d_in[0];   // (1,B,H)
    const float* enc    = (const float*)d_in[1];   // (T,B,H)
    const float* W      = (const float*)d_in[2];   // (H,2H)
    const float* b_attn = (const float*)d_in[3];   // (H,)
    const float* v      = (const float*)d_in[4];   // (H,)
    float* out = (float*)d_out;                    // (B,1,T)

    char* base = (char*)d_ws;
    short* W2p = (short*)base;                          // 512*512*2 = 524288 B
    float* hb  = (float*)(base + 524288);               // 32*512*4  =  65536 B
    float* sp  = (float*)(base + 524288 + 65536);       // 4*32*2048*4 = 1048576 B

    pack_w2_kernel<<<1024, 256, 0, stream>>>(W, W2p);
    hb_kernel<<<64, 256, 0, stream>>>(hidden, W, b_attn, hb);
    attn_main_kernel<<<2048, 256, 0, stream>>>(enc, W2p, hb, v, sp);
    softmax_kernel<<<32, 256, 0, stream>>>(sp, out);
}